// Round 4
// baseline (1598.277 us; speedup 1.0000x reference)
//
#include <hip/hip_runtime.h>
#include <hip/hip_bf16.h>
#include <math.h>

#define MOTIF  283
#define KPAD   288
#define HIDDEN 256
#define DEPTH  7
#define KPROF  20
#define CHUNK  512
#define NCHUNK 256
#define NTOK   131072
#define BK     32

using bf16 = __hip_bfloat16;
typedef short bf16x8 __attribute__((ext_vector_type(8)));
typedef float f32x4  __attribute__((ext_vector_type(4)));

__device__ __forceinline__ float gelu_res(float c){
  return 0.5f * c * (1.0f + erff(c * 0.70710678118654752f)) + c;   // gelu(c)+c
}

// ------------------------------------------------------------- prep kernels
// wtowT[layer][tap][co][ci] (bf16) from tower_w[layer][co][ci][tap] (f32)
__global__ __launch_bounds__(256) void k_prep_tower(
    const float* __restrict__ w, bf16* __restrict__ wt){
  const int idx = blockIdx.x * 256 + threadIdx.x;
  if (idx < DEPTH * 3 * HIDDEN * HIDDEN){
    const int ci   = idx & 255;
    const int co   = (idx >> 8) & 255;
    const int rest = idx >> 16;            // layer*3 + tap
    const int layer = rest / 3, tap = rest % 3;
    wt[idx] = __float2bfloat16(
        w[(((size_t)layer * HIDDEN + co) * HIDDEN + ci) * 3 + tap]);
  }
}

// wprojT[co][KPAD] bf16, zero-padded m>=283
__global__ __launch_bounds__(256) void k_prep_wproj(
    const float* __restrict__ w, bf16* __restrict__ wt){
  const int idx = blockIdx.x * 256 + threadIdx.x;
  if (idx < HIDDEN * KPAD){
    const int co = idx / KPAD, m = idx % KPAD;
    wt[idx] = __float2bfloat16(m < MOTIF ? w[(size_t)co * MOTIF + m] : 0.0f);
  }
}

// wheadT[k][ci] bf16: rows 0..19 = wprof[ci][k], row 20 = watpm[ci], 21..31 = 0
__global__ __launch_bounds__(256) void k_prep_whead(
    const float* __restrict__ wprof, const float* __restrict__ watpm,
    bf16* __restrict__ wh){
  const int idx = blockIdx.x * 256 + threadIdx.x;
  if (idx < 32 * 256){
    const int k = idx >> 8, ci = idx & 255;
    float v = 0.0f;
    if (k < KPROF) v = wprof[ci * KPROF + k];
    else if (k == KPROF) v = watpm[ci];
    wh[idx] = __float2bfloat16(v);
  }
}

// ------------------------------------------------------------- projection
// h0[token][co] = sum_m x[token][m] * wproj[co][m]
// block: ALL 256 co x 64 tok; stage full-K X tile once, then barrier-free K-loop
__global__ __launch_bounds__(256, 3) void k_proj(
    const float* __restrict__ x, const bf16* __restrict__ wprojT,
    bf16* __restrict__ h0){
  __shared__ __align__(16) bf16 Xs[64 * KPAD];   // 36 KB
  const int t0  = blockIdx.x * 64;
  const int tid = threadIdx.x;
  const int wid = tid >> 6, lane = tid & 63;
  const int lr = lane & 15, kq = lane >> 4;
  const int cow = wid * 64;

  for (int r = wid; r < 64; r += 4){
    const float* xrow = x + (size_t)(t0 + r) * MOTIF;
    #pragma unroll
    for (int mi = 0; mi < 5; ++mi){
      const int m = lane + mi * 64;
      if (m < KPAD)
        Xs[r * KPAD + m] = __float2bfloat16(m < MOTIF ? xrow[m] : 0.0f);
    }
  }
  __syncthreads();

  f32x4 acc[4][4];
  #pragma unroll
  for (int mt = 0; mt < 4; ++mt)
    #pragma unroll
    for (int nt = 0; nt < 4; ++nt) acc[mt][nt] = (f32x4){0.f, 0.f, 0.f, 0.f};

  for (int m0 = 0; m0 < KPAD; m0 += BK){
    bf16x8 a[4], b[4];
    #pragma unroll
    for (int mt = 0; mt < 4; ++mt)
      a[mt] = *(const bf16x8*)(
          wprojT + (size_t)(cow + mt * 16 + lr) * KPAD + m0 + kq * 8);
    #pragma unroll
    for (int nt = 0; nt < 4; ++nt)
      b[nt] = *(const bf16x8*)(Xs + (nt * 16 + lr) * KPAD + m0 + kq * 8);
    #pragma unroll
    for (int mt = 0; mt < 4; ++mt)
      #pragma unroll
      for (int nt = 0; nt < 4; ++nt)
        acc[mt][nt] = __builtin_amdgcn_mfma_f32_16x16x32_bf16(
            a[mt], b[nt], acc[mt][nt], 0, 0, 0);
  }

  #pragma unroll
  for (int mt = 0; mt < 4; ++mt){
    const int co = cow + mt * 16 + kq * 4;
    #pragma unroll
    for (int nt = 0; nt < 4; ++nt){
      const int tok = t0 + nt * 16 + lr;
      bf16 ov[4];
      #pragma unroll
      for (int r = 0; r < 4; ++r) ov[r] = __float2bfloat16(acc[mt][nt][r]);
      *(uint2*)(h0 + (size_t)tok * HIDDEN + co) = *(uint2*)ov;
    }
  }
}

// ------------------------------------------------------------- conv tower
// hout[l][co] = gelu(c)+c, c = bias[co] + sum_{tap,ci} W[tap][co][ci]*h[l+(tap-1)d][ci]
// NO LDS, NO barriers: B fragments load direct from global ([l][ci] layout IS
// the MFMA B layout); A direct from L2-hot weights. 4 waves/SIMD target.
__global__ __launch_bounds__(256, 4) void k_conv(
    const bf16* __restrict__ hin, bf16* __restrict__ hout,
    const bf16* __restrict__ wl,     // [3][256 co][256 ci]
    const float* __restrict__ bias, int dil){
  const int n  = blockIdx.y;
  const int l0 = blockIdx.x * 64;
  const int tid = threadIdx.x;
  const int wid = tid >> 6, lane = tid & 63;
  const int lr = lane & 15, kq = lane >> 4;
  const int cow = wid * 64;

  f32x4 acc[4][4];
  #pragma unroll
  for (int mt = 0; mt < 4; ++mt)
    #pragma unroll
    for (int nt = 0; nt < 4; ++nt) acc[mt][nt] = (f32x4){0.f, 0.f, 0.f, 0.f};

  const bf16* hbase = hin + (size_t)n * CHUNK * HIDDEN;
  const bf16x8 bz = {0, 0, 0, 0, 0, 0, 0, 0};

  for (int ci0 = 0; ci0 < HIDDEN; ci0 += BK){
    #pragma unroll
    for (int tap = 0; tap < 3; ++tap){
      const int s = (tap - 1) * dil;
      if (l0 + s >= CHUNK || l0 + 64 + s <= 0) continue;   // wave-uniform skip
      bf16x8 a[4], b[4];
      #pragma unroll
      for (int nt = 0; nt < 4; ++nt){
        const int l = l0 + nt * 16 + lr + s;
        b[nt] = ((unsigned)l < CHUNK)
              ? *(const bf16x8*)(hbase + ((size_t)l << 8) + ci0 + kq * 8)
              : bz;
      }
      #pragma unroll
      for (int mt = 0; mt < 4; ++mt)
        a[mt] = *(const bf16x8*)(
            wl + ((size_t)(tap * 256 + cow + mt * 16 + lr) << 8) + ci0 + kq * 8);
      #pragma unroll
      for (int mt = 0; mt < 4; ++mt)
        #pragma unroll
        for (int nt = 0; nt < 4; ++nt)
          acc[mt][nt] = __builtin_amdgcn_mfma_f32_16x16x32_bf16(
              a[mt], b[nt], acc[mt][nt], 0, 0, 0);
    }
  }

  bf16* obase = hout + (size_t)n * CHUNK * HIDDEN;
  #pragma unroll
  for (int mt = 0; mt < 4; ++mt){
    const int co = cow + mt * 16 + kq * 4;
    const float b0 = bias[co], b1 = bias[co + 1];
    const float b2 = bias[co + 2], b3 = bias[co + 3];
    #pragma unroll
    for (int nt = 0; nt < 4; ++nt){
      const int l = l0 + nt * 16 + lr;
      bf16 ov[4];
      ov[0] = __float2bfloat16(gelu_res(acc[mt][nt][0] + b0));
      ov[1] = __float2bfloat16(gelu_res(acc[mt][nt][1] + b1));
      ov[2] = __float2bfloat16(gelu_res(acc[mt][nt][2] + b2));
      ov[3] = __float2bfloat16(gelu_res(acc[mt][nt][3] + b3));
      *(uint2*)(obase + (size_t)l * HIDDEN + co) = *(uint2*)ov;
    }
  }
}

// ------------------------------------------------------------- head GEMM
// PT[k][token] = sum_ci h[token][ci] * wheadT[k][ci]   (k 0..31, 21 useful)
__global__ __launch_bounds__(256, 2) void k_head(
    const bf16* __restrict__ h, const bf16* __restrict__ wheadT,
    float* __restrict__ PT){
  __shared__ __align__(16) bf16 Xs[128 * BK];     // 8 KB
  __shared__ __align__(16) bf16 Wh[32 * 256];     // 16 KB
  const int t0 = blockIdx.x * 128;
  const int tid = threadIdx.x;
  const int wid = tid >> 6, lane = tid & 63;
  const int lr = lane & 15, kq = lane >> 4;
  const int mw = wid & 1, nw = wid >> 1;

  for (int i = tid; i < 1024; i += 256)
    ((uint4*)Wh)[i] = ((const uint4*)wheadT)[i];

  f32x4 acc[4];
  #pragma unroll
  for (int mt = 0; mt < 4; ++mt) acc[mt] = (f32x4){0.f, 0.f, 0.f, 0.f};

  for (int ci0 = 0; ci0 < HIDDEN; ci0 += BK){
    __syncthreads();
    for (int i = tid; i < 512; i += 256){
      const int row = i >> 2, q = i & 3;
      *(uint4*)(Xs + row * BK + q * 8) =
          *(const uint4*)(h + (size_t)(t0 + row) * HIDDEN + ci0 + q * 8);
    }
    __syncthreads();
    const bf16x8 b = *(const bf16x8*)(Wh + (nw * 16 + lr) * 256 + ci0 + kq * 8);
    #pragma unroll
    for (int mt = 0; mt < 4; ++mt){
      const bf16x8 a = *(const bf16x8*)(Xs + (mw * 64 + mt * 16 + lr) * BK + kq * 8);
      acc[mt] = __builtin_amdgcn_mfma_f32_16x16x32_bf16(a, b, acc[mt], 0, 0, 0);
    }
  }
  const int k_out = nw * 16 + lr;
  #pragma unroll
  for (int mt = 0; mt < 4; ++mt){
    const int tok = t0 + mw * 64 + mt * 16 + kq * 4;
    *(f32x4*)(PT + (size_t)k_out * NTOK + tok) = acc[mt];
  }
}

// ------------------------------------------------------------- tap combine
__global__ __launch_bounds__(256) void k_combine(
    const float* __restrict__ PT, const float* __restrict__ bprof,
    float* __restrict__ out){
  const int t = blockIdx.x * 256 + threadIdx.x;
  const int n = t >> 9, l = t & 511;
  float acc = bprof[0];
  const float* base = PT + ((size_t)n << 9);
  #pragma unroll
  for (int k = 0; k < KPROF; ++k){
    const int j = l + k - 9;
    if ((unsigned)j < CHUNK) acc += base[(size_t)k * NTOK + j];
  }
  out[NCHUNK + t] = acc;
}

// ------------------------------------------------------------- atpm pool
__global__ __launch_bounds__(256) void k_atpm(
    const float* __restrict__ PT, const float* __restrict__ batpm,
    const int* __restrict__ n_peaks, float* __restrict__ out){
  __shared__ float red[4];
  const int n = blockIdx.x, tid = threadIdx.x;
  const float* row = PT + (size_t)KPROF * NTOK + ((size_t)n << 9);
  float p = row[tid] + row[tid + 256];
  #pragma unroll
  for (int off = 32; off > 0; off >>= 1) p += __shfl_down(p, off, 64);
  if ((tid & 63) == 0) red[tid >> 6] = p;
  __syncthreads();
  if (tid == 0){
    const float s = red[0] + red[1] + red[2] + red[3];
    const float a = s * (1.0f / 512.0f) + batpm[0];
    out[n] = ((n & 127) < n_peaks[n >> 7]) ? a : 0.0f;
  }
}

// ------------------------------------------------------------- launcher
extern "C" void kernel_launch(void* const* d_in, const int* in_sizes, int n_in,
                              void* d_out, int out_size, void* d_ws, size_t ws_size,
                              hipStream_t stream){
  const float* x       = (const float*)d_in[0];
  const float* w_proj  = (const float*)d_in[1];
  const float* tower_w = (const float*)d_in[2];
  const float* tower_b = (const float*)d_in[3];
  const float* w_prof  = (const float*)d_in[4];
  const float* b_prof  = (const float*)d_in[5];
  const float* w_atpm  = (const float*)d_in[6];
  const float* b_atpm  = (const float*)d_in[7];
  const int*   n_peaks = (const int*)d_in[8];
  float* out = (float*)d_out;

  char* ws = (char*)d_ws;
  bf16*  h0     = (bf16*)ws;                        // 67108864 B
  bf16*  h1     = (bf16*)(ws + 67108864);           // 67108864 B
  float* PT     = (float*)(ws + 134217728);         // 16777216 B
  bf16*  wtowT  = (bf16*)(ws + 150994944);          // 2752512 B
  bf16*  wheadT = (bf16*)(ws + 153747456);          // 16384 B
  bf16*  wprojT = (bf16*)(ws + 153763840);          // 147456 B

  k_prep_tower<<<5376, 256, 0, stream>>>(tower_w, wtowT);
  k_prep_wproj<<<(HIDDEN * KPAD + 255) / 256, 256, 0, stream>>>(w_proj, wprojT);
  k_prep_whead<<<32, 256, 0, stream>>>(w_prof, w_atpm, wheadT);

  k_proj<<<NTOK / 64, 256, 0, stream>>>(x, wprojT, h0);

  bf16* cur = h0; bf16* nxt = h1;
  for (int i = 0; i < DEPTH; ++i){
    k_conv<<<dim3(CHUNK / 64, NCHUNK), 256, 0, stream>>>(
        cur, nxt, wtowT + (size_t)i * 3 * HIDDEN * HIDDEN,
        tower_b + i * HIDDEN, 2 << i);
    bf16* t = cur; cur = nxt; nxt = t;
  }

  k_head<<<1024, 256, 0, stream>>>(cur, wheadT, PT);
  k_combine<<<512, 256, 0, stream>>>(PT, b_prof, out);
  k_atpm<<<256, 256, 0, stream>>>(PT, b_atpm, n_peaks, out);
}

// Round 5
// 1551.874 us; speedup vs baseline: 1.0299x; 1.0299x over previous
//
#include <hip/hip_runtime.h>
#include <hip/hip_bf16.h>
#include <math.h>

#define MOTIF  283
#define KPAD   288
#define HIDDEN 256
#define DEPTH  7
#define KPROF  20
#define CHUNK  512
#define NCHUNK 256
#define NTOK   131072
#define BK     32
#define XPITCH 40          // padded LDS row pitch (bf16): 80 B, breaks bank cycles

using bf16 = __hip_bfloat16;
typedef short bf16x8 __attribute__((ext_vector_type(8)));
typedef float f32x4  __attribute__((ext_vector_type(4)));

__device__ __forceinline__ float gelu_res(float c){
  return 0.5f * c * (1.0f + erff(c * 0.70710678118654752f)) + c;   // gelu(c)+c
}

// ------------------------------------------------------------- prep kernels
// MFMA-fragment-swizzled tower weights:
// wfrag[layer][ci0c(8)][tap(3)][ch(2)][mt(8)][lane(64)][e(8)]
//   = W[tap][co = ch*128+mt*16+(lane&15)][ci = ci0c*32+(lane>>4)*8+e]
// so one wave A-load = contiguous 1 KB.
__global__ __launch_bounds__(256) void k_prep_wfrag(
    const float* __restrict__ w, bf16* __restrict__ wf){
  const int idx = blockIdx.x * 256 + threadIdx.x;
  if (idx < DEPTH * 196608){
    const int layer = idx / 196608;
    const int r     = idx % 196608;
    const int e    = r & 7;
    const int lane = (r >> 3) & 63;
    const int mt   = (r >> 9) & 7;
    const int t3   = r >> 12;
    const int ch   = t3 & 1;
    const int t4   = t3 >> 1;
    const int tap  = t4 % 3;
    const int ci0c = t4 / 3;
    const int co = ch * 128 + mt * 16 + (lane & 15);
    const int ci = ci0c * 32 + (lane >> 4) * 8 + e;
    wf[idx] = __float2bfloat16(
        w[(((size_t)layer * HIDDEN + co) * HIDDEN + ci) * 3 + tap]);
  }
}

// wprojT[co][KPAD] bf16, zero-padded m>=283
__global__ __launch_bounds__(256) void k_prep_wproj(
    const float* __restrict__ w, bf16* __restrict__ wt){
  const int idx = blockIdx.x * 256 + threadIdx.x;
  if (idx < HIDDEN * KPAD){
    const int co = idx / KPAD, m = idx % KPAD;
    wt[idx] = __float2bfloat16(m < MOTIF ? w[(size_t)co * MOTIF + m] : 0.0f);
  }
}

// wheadT[k][ci] bf16: rows 0..19 = wprof[ci][k], row 20 = watpm[ci], 21..31 = 0
__global__ __launch_bounds__(256) void k_prep_whead(
    const float* __restrict__ wprof, const float* __restrict__ watpm,
    bf16* __restrict__ wh){
  const int idx = blockIdx.x * 256 + threadIdx.x;
  if (idx < 32 * 256){
    const int k = idx >> 8, ci = idx & 255;
    float v = 0.0f;
    if (k < KPROF) v = wprof[ci * KPROF + k];
    else if (k == KPROF) v = watpm[ci];
    wh[idx] = __float2bfloat16(v);
  }
}

// ------------------------------------------------------------- projection
__global__ __launch_bounds__(256, 3) void k_proj(
    const float* __restrict__ x, const bf16* __restrict__ wprojT,
    bf16* __restrict__ h0){
  __shared__ __align__(16) bf16 Xs[64 * KPAD];   // 36 KB
  const int t0  = blockIdx.x * 64;
  const int tid = threadIdx.x;
  const int wid = tid >> 6, lane = tid & 63;
  const int lr = lane & 15, kq = lane >> 4;
  const int cow = wid * 64;

  for (int r = wid; r < 64; r += 4){
    const float* xrow = x + (size_t)(t0 + r) * MOTIF;
    #pragma unroll
    for (int mi = 0; mi < 5; ++mi){
      const int m = lane + mi * 64;
      if (m < KPAD)
        Xs[r * KPAD + m] = __float2bfloat16(m < MOTIF ? xrow[m] : 0.0f);
    }
  }
  __syncthreads();

  f32x4 acc[4][4];
  #pragma unroll
  for (int mt = 0; mt < 4; ++mt)
    #pragma unroll
    for (int nt = 0; nt < 4; ++nt) acc[mt][nt] = (f32x4){0.f, 0.f, 0.f, 0.f};

  for (int m0 = 0; m0 < KPAD; m0 += BK){
    bf16x8 a[4], b[4];
    #pragma unroll
    for (int mt = 0; mt < 4; ++mt)
      a[mt] = *(const bf16x8*)(
          wprojT + (size_t)(cow + mt * 16 + lr) * KPAD + m0 + kq * 8);
    #pragma unroll
    for (int nt = 0; nt < 4; ++nt)
      b[nt] = *(const bf16x8*)(Xs + (nt * 16 + lr) * KPAD + m0 + kq * 8);
    #pragma unroll
    for (int mt = 0; mt < 4; ++mt)
      #pragma unroll
      for (int nt = 0; nt < 4; ++nt)
        acc[mt][nt] = __builtin_amdgcn_mfma_f32_16x16x32_bf16(
            a[mt], b[nt], acc[mt][nt], 0, 0, 0);
  }

  #pragma unroll
  for (int mt = 0; mt < 4; ++mt){
    const int co = cow + mt * 16 + kq * 4;
    #pragma unroll
    for (int nt = 0; nt < 4; ++nt){
      const int tok = t0 + nt * 16 + lr;
      bf16 ov[4];
      #pragma unroll
      for (int r = 0; r < 4; ++r) ov[r] = __float2bfloat16(acc[mt][nt][r]);
      *(uint2*)(h0 + (size_t)tok * HIDDEN + co) = *(uint2*)ov;
    }
  }
}

// ------------------------------------------------------------- conv tower
// Block: 512 thr = 8 waves, tile 256co x 256l; wave = 128co x 64l.
// X staged in LDS (padded pitch 40); A direct-global from fragment-swizzled
// weights (one contiguous 1KB load per wave per fragment).
__global__ __launch_bounds__(512, 2) void k_conv(
    const bf16* __restrict__ hin, bf16* __restrict__ hout,
    const bf16* __restrict__ wf,     // swizzled layer weights
    const float* __restrict__ bias, int dil){
  __shared__ __align__(16) bf16 Xs[3 * 256 * XPITCH];   // 60 KB
  const int n  = blockIdx.y;
  const int l0 = blockIdx.x * 256;
  const int tid = threadIdx.x;
  const int w   = tid >> 6, lane = tid & 63;
  const int lr = lane & 15, kq = lane >> 4;
  const int ch = w & 1;          // co half (128)
  const int lq = w >> 1;         // l quarter (64)
  const int wl0 = l0 + lq * 64;

  f32x4 acc[8][4];
  #pragma unroll
  for (int mt = 0; mt < 8; ++mt)
    #pragma unroll
    for (int nt = 0; nt < 4; ++nt) acc[mt][nt] = (f32x4){0.f, 0.f, 0.f, 0.f};

  const bf16* hbase = hin + (size_t)n * CHUNK * HIDDEN;

  for (int ci0 = 0; ci0 < HIDDEN; ci0 += BK){
    __syncthreads();
    // stage 3 taps x 256 l x 32 ci, zero-padded OOB
    for (int i = tid; i < 3072; i += 512){
      const int row = i >> 2, q = i & 3;        // row = tap*256 + j
      const int tap = row >> 8, j = row & 255;
      const int l = l0 + j + (tap - 1) * dil;
      uint4 v = {0u, 0u, 0u, 0u};
      if ((unsigned)l < CHUNK)
        v = *(const uint4*)(hbase + ((size_t)l << 8) + ci0 + q * 8);
      *(uint4*)(Xs + row * XPITCH + q * 8) = v;
    }
    __syncthreads();

    const bf16* wci = wf + (size_t)(ci0 >> 5) * 24576 + (size_t)ch * 4096;
    #pragma unroll
    for (int tap = 0; tap < 3; ++tap){
      const int s = (tap - 1) * dil;
      if (wl0 + s >= CHUNK || wl0 + 63 + s < 0) continue;  // wave-uniform skip
      const bf16* wt = wci + (size_t)tap * 8192 + lane * 8;
      bf16x8 b[4];
      #pragma unroll
      for (int nt = 0; nt < 4; ++nt)
        b[nt] = *(const bf16x8*)(
            Xs + (tap * 256 + lq * 64 + nt * 16 + lr) * XPITCH + kq * 8);
      #pragma unroll
      for (int mt = 0; mt < 8; ++mt){
        const bf16x8 a = *(const bf16x8*)(wt + mt * 512);
        #pragma unroll
        for (int nt = 0; nt < 4; ++nt)
          acc[mt][nt] = __builtin_amdgcn_mfma_f32_16x16x32_bf16(
              a, b[nt], acc[mt][nt], 0, 0, 0);
      }
    }
  }

  bf16* obase = hout + (size_t)n * CHUNK * HIDDEN;
  #pragma unroll
  for (int mt = 0; mt < 8; ++mt){
    const int co = ch * 128 + mt * 16 + kq * 4;
    const float b0 = bias[co], b1 = bias[co + 1];
    const float b2 = bias[co + 2], b3 = bias[co + 3];
    #pragma unroll
    for (int nt = 0; nt < 4; ++nt){
      const int l = wl0 + nt * 16 + lr;
      bf16 ov[4];
      ov[0] = __float2bfloat16(gelu_res(acc[mt][nt][0] + b0));
      ov[1] = __float2bfloat16(gelu_res(acc[mt][nt][1] + b1));
      ov[2] = __float2bfloat16(gelu_res(acc[mt][nt][2] + b2));
      ov[3] = __float2bfloat16(gelu_res(acc[mt][nt][3] + b3));
      *(uint2*)(obase + (size_t)l * HIDDEN + co) = *(uint2*)ov;
    }
  }
}

// ------------------------------------------------------------- head GEMM
__global__ __launch_bounds__(256, 2) void k_head(
    const bf16* __restrict__ h, const bf16* __restrict__ wheadT,
    float* __restrict__ PT){
  __shared__ __align__(16) bf16 Xs[128 * BK];     // 8 KB
  __shared__ __align__(16) bf16 Wh[32 * 256];     // 16 KB
  const int t0 = blockIdx.x * 128;
  const int tid = threadIdx.x;
  const int wid = tid >> 6, lane = tid & 63;
  const int lr = lane & 15, kq = lane >> 4;
  const int mw = wid & 1, nw = wid >> 1;

  for (int i = tid; i < 1024; i += 256)
    ((uint4*)Wh)[i] = ((const uint4*)wheadT)[i];

  f32x4 acc[4];
  #pragma unroll
  for (int mt = 0; mt < 4; ++mt) acc[mt] = (f32x4){0.f, 0.f, 0.f, 0.f};

  for (int ci0 = 0; ci0 < HIDDEN; ci0 += BK){
    __syncthreads();
    for (int i = tid; i < 512; i += 256){
      const int row = i >> 2, q = i & 3;
      *(uint4*)(Xs + row * BK + q * 8) =
          *(const uint4*)(h + (size_t)(t0 + row) * HIDDEN + ci0 + q * 8);
    }
    __syncthreads();
    const bf16x8 b = *(const bf16x8*)(Wh + (nw * 16 + lr) * 256 + ci0 + kq * 8);
    #pragma unroll
    for (int mt = 0; mt < 4; ++mt){
      const bf16x8 a = *(const bf16x8*)(Xs + (mw * 64 + mt * 16 + lr) * BK + kq * 8);
      acc[mt] = __builtin_amdgcn_mfma_f32_16x16x32_bf16(a, b, acc[mt], 0, 0, 0);
    }
  }
  const int k_out = nw * 16 + lr;
  #pragma unroll
  for (int mt = 0; mt < 4; ++mt){
    const int tok = t0 + mw * 64 + mt * 16 + kq * 4;
    *(f32x4*)(PT + (size_t)k_out * NTOK + tok) = acc[mt];
  }
}

// ------------------------------------------------------------- tap combine
__global__ __launch_bounds__(256) void k_combine(
    const float* __restrict__ PT, const float* __restrict__ bprof,
    float* __restrict__ out){
  const int t = blockIdx.x * 256 + threadIdx.x;
  const int n = t >> 9, l = t & 511;
  float acc = bprof[0];
  const float* base = PT + ((size_t)n << 9);
  #pragma unroll
  for (int k = 0; k < KPROF; ++k){
    const int j = l + k - 9;
    if ((unsigned)j < CHUNK) acc += base[(size_t)k * NTOK + j];
  }
  out[NCHUNK + t] = acc;
}

// ------------------------------------------------------------- atpm pool
__global__ __launch_bounds__(256) void k_atpm(
    const float* __restrict__ PT, const float* __restrict__ batpm,
    const int* __restrict__ n_peaks, float* __restrict__ out){
  __shared__ float red[4];
  const int n = blockIdx.x, tid = threadIdx.x;
  const float* row = PT + (size_t)KPROF * NTOK + ((size_t)n << 9);
  float p = row[tid] + row[tid + 256];
  #pragma unroll
  for (int off = 32; off > 0; off >>= 1) p += __shfl_down(p, off, 64);
  if ((tid & 63) == 0) red[tid >> 6] = p;
  __syncthreads();
  if (tid == 0){
    const float s = red[0] + red[1] + red[2] + red[3];
    const float a = s * (1.0f / 512.0f) + batpm[0];
    out[n] = ((n & 127) < n_peaks[n >> 7]) ? a : 0.0f;
  }
}

// ------------------------------------------------------------- launcher
extern "C" void kernel_launch(void* const* d_in, const int* in_sizes, int n_in,
                              void* d_out, int out_size, void* d_ws, size_t ws_size,
                              hipStream_t stream){
  const float* x       = (const float*)d_in[0];
  const float* w_proj  = (const float*)d_in[1];
  const float* tower_w = (const float*)d_in[2];
  const float* tower_b = (const float*)d_in[3];
  const float* w_prof  = (const float*)d_in[4];
  const float* b_prof  = (const float*)d_in[5];
  const float* w_atpm  = (const float*)d_in[6];
  const float* b_atpm  = (const float*)d_in[7];
  const int*   n_peaks = (const int*)d_in[8];
  float* out = (float*)d_out;

  char* ws = (char*)d_ws;
  bf16*  h0     = (bf16*)ws;                        // 67108864 B
  bf16*  h1     = (bf16*)(ws + 67108864);           // 67108864 B
  float* PT     = (float*)(ws + 134217728);         // 16777216 B
  bf16*  wfrag  = (bf16*)(ws + 150994944);          // 2752512 B
  bf16*  wheadT = (bf16*)(ws + 153747456);          // 16384 B
  bf16*  wprojT = (bf16*)(ws + 153763840);          // 147456 B

  k_prep_wfrag<<<5376, 256, 0, stream>>>(tower_w, wfrag);
  k_prep_wproj<<<(HIDDEN * KPAD + 255) / 256, 256, 0, stream>>>(w_proj, wprojT);
  k_prep_whead<<<32, 256, 0, stream>>>(w_prof, w_atpm, wheadT);

  k_proj<<<NTOK / 64, 256, 0, stream>>>(x, wprojT, h0);

  bf16* cur = h0; bf16* nxt = h1;
  for (int i = 0; i < DEPTH; ++i){
    k_conv<<<dim3(2, NCHUNK), 512, 0, stream>>>(
        cur, nxt, wfrag + (size_t)i * 3 * HIDDEN * HIDDEN,
        tower_b + i * HIDDEN, 2 << i);
    bf16* t = cur; cur = nxt; nxt = t;
  }

  k_head<<<1024, 256, 0, stream>>>(cur, wheadT, PT);
  k_combine<<<512, 256, 0, stream>>>(PT, b_prof, out);
  k_atpm<<<256, 256, 0, stream>>>(PT, b_atpm, n_peaks, out);
}

// Round 6
// 946.884 us; speedup vs baseline: 1.6879x; 1.6389x over previous
//
#include <hip/hip_runtime.h>
#include <hip/hip_bf16.h>
#include <math.h>

#define MOTIF  283
#define KPAD   288
#define HIDDEN 256
#define DEPTH  7
#define KPROF  20
#define CHUNK  512
#define NCHUNK 256
#define NTOK   131072
#define BK     32

using bf16 = __hip_bfloat16;
typedef short bf16x8 __attribute__((ext_vector_type(8)));
typedef float f32x4  __attribute__((ext_vector_type(4)));

// async global->LDS, 16B per lane; LDS dest = wave-uniform base + lane*16
#define GLD_LDS(g, l) __builtin_amdgcn_global_load_lds( \
    (const __attribute__((address_space(1))) void*)(g), \
    (__attribute__((address_space(3))) void*)(l), 16, 0, 0)

__device__ __forceinline__ float gelu_res(float c){
  return 0.5f * c * (1.0f + erff(c * 0.70710678118654752f)) + c;   // gelu(c)+c
}

// ------------------------------------------------------------- prep kernels
// wtowT[layer][tap][co][ci] (bf16) from tower_w[layer][co][ci][tap] (f32)
__global__ __launch_bounds__(256) void k_prep_tower(
    const float* __restrict__ w, bf16* __restrict__ wt){
  const int idx = blockIdx.x * 256 + threadIdx.x;
  if (idx < DEPTH * 3 * HIDDEN * HIDDEN){
    const int ci = idx & 255;
    const int co = (idx >> 8) & 255;
    const int lt = idx >> 16;             // layer*3 + tap
    const int layer = lt / 3, tap = lt % 3;
    wt[idx] = __float2bfloat16(
        w[(((size_t)layer * HIDDEN + co) * HIDDEN + ci) * 3 + tap]);
  }
}

// wprojT[co][KPAD] bf16, zero-padded m>=283
__global__ __launch_bounds__(256) void k_prep_wproj(
    const float* __restrict__ w, bf16* __restrict__ wt){
  const int idx = blockIdx.x * 256 + threadIdx.x;
  if (idx < HIDDEN * KPAD){
    const int co = idx / KPAD, m = idx % KPAD;
    wt[idx] = __float2bfloat16(m < MOTIF ? w[(size_t)co * MOTIF + m] : 0.0f);
  }
}

// wheadT[k][ci] bf16 (rows 0..19 wprof, 20 watpm, 21..31 zero) + zero the
// 4 KB zero-page every call (ws is re-poisoned to 0xAA before each launch)
__global__ __launch_bounds__(256) void k_prep_whead(
    const float* __restrict__ wprof, const float* __restrict__ watpm,
    bf16* __restrict__ wh, bf16* __restrict__ zp){
  const int idx = blockIdx.x * 256 + threadIdx.x;
  if (idx < 2048) zp[idx] = __float2bfloat16(0.0f);
  if (idx < 32 * 256){
    const int k = idx >> 8, ci = idx & 255;
    float v = 0.0f;
    if (k < KPROF) v = wprof[ci * KPROF + k];
    else if (k == KPROF) v = watpm[ci];
    wh[idx] = __float2bfloat16(v);
  }
}

// ------------------------------------------------------------- projection
__global__ __launch_bounds__(256, 3) void k_proj(
    const float* __restrict__ x, const bf16* __restrict__ wprojT,
    bf16* __restrict__ h0){
  __shared__ __align__(16) bf16 Xs[64 * KPAD];   // 36 KB
  const int t0  = blockIdx.x * 64;
  const int tid = threadIdx.x;
  const int wid = tid >> 6, lane = tid & 63;
  const int lr = lane & 15, kq = lane >> 4;
  const int cow = wid * 64;

  for (int r = wid; r < 64; r += 4){
    const float* xrow = x + (size_t)(t0 + r) * MOTIF;
    #pragma unroll
    for (int mi = 0; mi < 5; ++mi){
      const int m = lane + mi * 64;
      if (m < KPAD)
        Xs[r * KPAD + m] = __float2bfloat16(m < MOTIF ? xrow[m] : 0.0f);
    }
  }
  __syncthreads();

  f32x4 acc[4][4];
  #pragma unroll
  for (int mt = 0; mt < 4; ++mt)
    #pragma unroll
    for (int nt = 0; nt < 4; ++nt) acc[mt][nt] = (f32x4){0.f, 0.f, 0.f, 0.f};

  for (int m0 = 0; m0 < KPAD; m0 += BK){
    bf16x8 a[4], b[4];
    #pragma unroll
    for (int mt = 0; mt < 4; ++mt)
      a[mt] = *(const bf16x8*)(
          wprojT + (size_t)(cow + mt * 16 + lr) * KPAD + m0 + kq * 8);
    #pragma unroll
    for (int nt = 0; nt < 4; ++nt)
      b[nt] = *(const bf16x8*)(Xs + (nt * 16 + lr) * KPAD + m0 + kq * 8);
    #pragma unroll
    for (int mt = 0; mt < 4; ++mt)
      #pragma unroll
      for (int nt = 0; nt < 4; ++nt)
        acc[mt][nt] = __builtin_amdgcn_mfma_f32_16x16x32_bf16(
            a[mt], b[nt], acc[mt][nt], 0, 0, 0);
  }

  #pragma unroll
  for (int mt = 0; mt < 4; ++mt){
    const int co = cow + mt * 16 + kq * 4;
    #pragma unroll
    for (int nt = 0; nt < 4; ++nt){
      const int tok = t0 + nt * 16 + lr;
      bf16 ov[4];
      #pragma unroll
      for (int r = 0; r < 4; ++r) ov[r] = __float2bfloat16(acc[mt][nt][r]);
      *(uint2*)(h0 + (size_t)tok * HIDDEN + co) = *(uint2*)ov;
    }
  }
}

// ------------------------------------------------------------- conv tower
// m97-shape GEMM: tile 128co x 128l, 4 waves 2x2 (64x64 each, acc 4x4 = 64
// AGPR), A+B staged via global_load_lds(16B), 2-barrier K-loop (8 iters of
// BK=32, 3 taps inside). XOR column swizzle (cc = c ^ (row&3)) applied on the
// GLOBAL side so LDS stays lane-contiguous for global_load_lds yet fragment
// ds_read_b128s are bank-conflict-free. OOB tap rows read a zero page.
__global__ __launch_bounds__(256, 3) void k_conv(
    const bf16* __restrict__ hin, bf16* __restrict__ hout,
    const bf16* __restrict__ wl,     // [3][256 co][256 ci] this layer
    const float* __restrict__ bias, const bf16* __restrict__ zp, int dil){
  __shared__ __align__(16) bf16 As[3 * 128 * BK];   // 24 KB [tap][co_r][ci]
  __shared__ __align__(16) bf16 Bs[3 * 128 * BK];   // 24 KB [tap][l_r][ci]
  const int n   = blockIdx.z;
  const int co0 = blockIdx.y * 128;
  const int l0  = blockIdx.x * 128;
  const int tid = threadIdx.x;
  const int wid = tid >> 6, lane = tid & 63;
  const int lr = lane & 15, kq = lane >> 4;
  const int mw = wid & 1, nw = wid >> 1;

  const bf16* hbase = hin + (size_t)n * CHUNK * HIDDEN;

  // per-thread staging pointers (advance by BK elems per K-iter)
  const bf16* gA[6]; const bf16* gB[6]; int stepB[6];
  #pragma unroll
  for (int j = 0; j < 6; ++j){
    const int i   = j * 256 + tid;
    const int row = i >> 2, c = i & 3;
    const int cc  = c ^ (row & 3);          // global-side XOR swizzle
    const int tap = row >> 7;
    const int r   = row & 127;
    gA[j] = wl + ((size_t)(tap * 256 + co0 + r) << 8) + cc * 8;
    const int l = l0 + r + (tap - 1) * dil;
    const bool v = (unsigned)l < CHUNK;
    gB[j] = v ? hbase + ((size_t)l << 8) + cc * 8 : zp + ((i & 255) * 8);
    stepB[j] = v ? BK : 0;
  }

  f32x4 acc[4][4];
  #pragma unroll
  for (int mt = 0; mt < 4; ++mt)
    #pragma unroll
    for (int nt = 0; nt < 4; ++nt) acc[mt][nt] = (f32x4){0.f, 0.f, 0.f, 0.f};

  // fragment read bases (constant across K-iters; tap/mt offsets fold to imm)
  const int sw = (kq ^ (lr & 3)) << 3;
  const bf16* Ab = As + (mw * 64 + lr) * BK + sw;
  const bf16* Bb = Bs + (nw * 64 + lr) * BK + sw;

  // block-uniform whole-tap skips (staging still runs; zeros are harmless)
  const bool do0 = (l0 + 127 - dil) >= 0;       // false only l0=0, dil=128
  const bool do2 = (l0 + dil) < CHUNK;          // false only l0=384, dil=128

  for (int it = 0; it < HIDDEN / BK; ++it){
    __syncthreads();
    #pragma unroll
    for (int j = 0; j < 6; ++j){
      GLD_LDS(gA[j], As + (j * 256 + wid * 64) * 8);
      GLD_LDS(gB[j], Bs + (j * 256 + wid * 64) * 8);
    }
    __syncthreads();

    #pragma unroll
    for (int t = 0; t < 3; ++t){
      if (t == 0 && !do0) continue;
      if (t == 2 && !do2) continue;
      bf16x8 a[4], b[4];
      #pragma unroll
      for (int mt = 0; mt < 4; ++mt)
        a[mt] = *(const bf16x8*)(Ab + t * 4096 + mt * 512);
      #pragma unroll
      for (int nt = 0; nt < 4; ++nt)
        b[nt] = *(const bf16x8*)(Bb + t * 4096 + nt * 512);
      #pragma unroll
      for (int mt = 0; mt < 4; ++mt)
        #pragma unroll
        for (int nt = 0; nt < 4; ++nt)
          acc[mt][nt] = __builtin_amdgcn_mfma_f32_16x16x32_bf16(
              a[mt], b[nt], acc[mt][nt], 0, 0, 0);
    }

    #pragma unroll
    for (int j = 0; j < 6; ++j){ gA[j] += BK; gB[j] += stepB[j]; }
  }

  bf16* obase = hout + (size_t)n * CHUNK * HIDDEN;
  #pragma unroll
  for (int mt = 0; mt < 4; ++mt){
    const int co = co0 + mw * 64 + mt * 16 + kq * 4;
    const float b0 = bias[co], b1 = bias[co + 1];
    const float b2 = bias[co + 2], b3 = bias[co + 3];
    #pragma unroll
    for (int nt = 0; nt < 4; ++nt){
      const int l = l0 + nw * 64 + nt * 16 + lr;
      bf16 ov[4];
      ov[0] = __float2bfloat16(gelu_res(acc[mt][nt][0] + b0));
      ov[1] = __float2bfloat16(gelu_res(acc[mt][nt][1] + b1));
      ov[2] = __float2bfloat16(gelu_res(acc[mt][nt][2] + b2));
      ov[3] = __float2bfloat16(gelu_res(acc[mt][nt][3] + b3));
      *(uint2*)(obase + (size_t)l * HIDDEN + co) = *(uint2*)ov;
    }
  }
}

// ------------------------------------------------------------- head GEMM
__global__ __launch_bounds__(256, 2) void k_head(
    const bf16* __restrict__ h, const bf16* __restrict__ wheadT,
    float* __restrict__ PT){
  __shared__ __align__(16) bf16 Xs[128 * BK];     // 8 KB
  __shared__ __align__(16) bf16 Wh[32 * 256];     // 16 KB
  const int t0 = blockIdx.x * 128;
  const int tid = threadIdx.x;
  const int wid = tid >> 6, lane = tid & 63;
  const int lr = lane & 15, kq = lane >> 4;
  const int mw = wid & 1, nw = wid >> 1;

  for (int i = tid; i < 1024; i += 256)
    ((uint4*)Wh)[i] = ((const uint4*)wheadT)[i];

  f32x4 acc[4];
  #pragma unroll
  for (int mt = 0; mt < 4; ++mt) acc[mt] = (f32x4){0.f, 0.f, 0.f, 0.f};

  for (int ci0 = 0; ci0 < HIDDEN; ci0 += BK){
    __syncthreads();
    for (int i = tid; i < 512; i += 256){
      const int row = i >> 2, q = i & 3;
      *(uint4*)(Xs + row * BK + q * 8) =
          *(const uint4*)(h + (size_t)(t0 + row) * HIDDEN + ci0 + q * 8);
    }
    __syncthreads();
    const bf16x8 b = *(const bf16x8*)(Wh + (nw * 16 + lr) * 256 + ci0 + kq * 8);
    #pragma unroll
    for (int mt = 0; mt < 4; ++mt){
      const bf16x8 a = *(const bf16x8*)(Xs + (mw * 64 + mt * 16 + lr) * BK + kq * 8);
      acc[mt] = __builtin_amdgcn_mfma_f32_16x16x32_bf16(a, b, acc[mt], 0, 0, 0);
    }
  }
  const int k_out = nw * 16 + lr;
  #pragma unroll
  for (int mt = 0; mt < 4; ++mt){
    const int tok = t0 + mw * 64 + mt * 16 + kq * 4;
    *(f32x4*)(PT + (size_t)k_out * NTOK + tok) = acc[mt];
  }
}

// ------------------------------------------------------------- tap combine
__global__ __launch_bounds__(256) void k_combine(
    const float* __restrict__ PT, const float* __restrict__ bprof,
    float* __restrict__ out){
  const int t = blockIdx.x * 256 + threadIdx.x;
  const int n = t >> 9, l = t & 511;
  float acc = bprof[0];
  const float* base = PT + ((size_t)n << 9);
  #pragma unroll
  for (int k = 0; k < KPROF; ++k){
    const int j = l + k - 9;
    if ((unsigned)j < CHUNK) acc += base[(size_t)k * NTOK + j];
  }
  out[NCHUNK + t] = acc;
}

// ------------------------------------------------------------- atpm pool
__global__ __launch_bounds__(256) void k_atpm(
    const float* __restrict__ PT, const float* __restrict__ batpm,
    const int* __restrict__ n_peaks, float* __restrict__ out){
  __shared__ float red[4];
  const int n = blockIdx.x, tid = threadIdx.x;
  const float* row = PT + (size_t)KPROF * NTOK + ((size_t)n << 9);
  float p = row[tid] + row[tid + 256];
  #pragma unroll
  for (int off = 32; off > 0; off >>= 1) p += __shfl_down(p, off, 64);
  if ((tid & 63) == 0) red[tid >> 6] = p;
  __syncthreads();
  if (tid == 0){
    const float s = red[0] + red[1] + red[2] + red[3];
    const float a = s * (1.0f / 512.0f) + batpm[0];
    out[n] = ((n & 127) < n_peaks[n >> 7]) ? a : 0.0f;
  }
}

// ------------------------------------------------------------- launcher
extern "C" void kernel_launch(void* const* d_in, const int* in_sizes, int n_in,
                              void* d_out, int out_size, void* d_ws, size_t ws_size,
                              hipStream_t stream){
  const float* x       = (const float*)d_in[0];
  const float* w_proj  = (const float*)d_in[1];
  const float* tower_w = (const float*)d_in[2];
  const float* tower_b = (const float*)d_in[3];
  const float* w_prof  = (const float*)d_in[4];
  const float* b_prof  = (const float*)d_in[5];
  const float* w_atpm  = (const float*)d_in[6];
  const float* b_atpm  = (const float*)d_in[7];
  const int*   n_peaks = (const int*)d_in[8];
  float* out = (float*)d_out;

  char* ws = (char*)d_ws;
  bf16*  h0     = (bf16*)ws;                        // 67108864 B
  bf16*  h1     = (bf16*)(ws + 67108864);           // 67108864 B
  float* PT     = (float*)(ws + 134217728);         // 16777216 B
  bf16*  wtowT  = (bf16*)(ws + 150994944);          // 2752512 B
  bf16*  wheadT = (bf16*)(ws + 153747456);          // 16384 B
  bf16*  wprojT = (bf16*)(ws + 153763840);          // 147456 B
  bf16*  zp     = (bf16*)(ws + 153911296);          // 4096 B zero page

  k_prep_tower<<<5376, 256, 0, stream>>>(tower_w, wtowT);
  k_prep_wproj<<<(HIDDEN * KPAD + 255) / 256, 256, 0, stream>>>(w_proj, wprojT);
  k_prep_whead<<<32, 256, 0, stream>>>(w_prof, w_atpm, wheadT, zp);

  k_proj<<<NTOK / 64, 256, 0, stream>>>(x, wprojT, h0);

  bf16* cur = h0; bf16* nxt = h1;
  for (int i = 0; i < DEPTH; ++i){
    k_conv<<<dim3(CHUNK / 128, 2, NCHUNK), 256, 0, stream>>>(
        cur, nxt, wtowT + (size_t)i * 3 * HIDDEN * HIDDEN,
        tower_b + i * HIDDEN, zp, 2 << i);
    bf16* t = cur; cur = nxt; nxt = t;
  }

  k_head<<<1024, 256, 0, stream>>>(cur, wheadT, PT);
  k_combine<<<512, 256, 0, stream>>>(PT, b_prof, out);
  k_atpm<<<256, 256, 0, stream>>>(PT, b_atpm, n_peaks, out);
}